// Round 11
// baseline (3862.431 us; speedup 1.0000x reference)
//
#include <hip/hip_runtime.h>
#include <stdint.h>

#define B_ 64
#define T_ 2048
#define H_ 128
#define G_ 512
#define NL 3
#define OUT_ 10
#define CHK 16
#define NCH (T_/CHK)

typedef __attribute__((ext_vector_type(8))) short bf16x8;
typedef __attribute__((ext_vector_type(4))) float f32x4;

#define MF(A,BW,C) __builtin_amdgcn_mfma_f32_16x16x32_bf16(A,BW,C,0,0,0)

__device__ __forceinline__ uint16_t f2bf(float f){
  union { float f; uint32_t u; } v; v.f = f;
  uint32_t u = v.u;
  uint32_t r = (u + 0x7FFFu + ((u >> 16) & 1u)) >> 16;
  return (uint16_t)r;
}

// Barrier WITHOUT vmcnt(0) drain: LDS ordering only.
__device__ __forceinline__ void wg_barrier(){
  asm volatile("s_waitcnt lgkmcnt(0)" ::: "memory");
  __builtin_amdgcn_sched_barrier(0);
  __builtin_amdgcn_s_barrier();
  __builtin_amdgcn_sched_barrier(0);
}

// ---------------------------------------------------------------- prep
// Weights pre-scaled per gate (i,f,o: -log2e; g: +2*log2e) so gates become
// rcp(1+exp2(x)); bias likewise pre-scaled (folded into MFMA C-init).
__global__ void prep_kernel(const float* __restrict__ x,
                            const float* __restrict__ wih, const float* __restrict__ whh,
                            const float* __restrict__ bih, const float* __restrict__ bhh,
                            uint16_t* __restrict__ A0, uint16_t* __restrict__ WIHS,
                            uint16_t* __restrict__ WHHS, float* __restrict__ BSCL,
                            int* __restrict__ flags){
  int stride = gridDim.x * blockDim.x;
  int g0 = blockIdx.x * blockDim.x + threadIdx.x;
  for (int i = g0; i < B_*T_*H_; i += stride) A0[i] = f2bf(x[i]);
  for (int i = g0; i < NL*G_*H_; i += stride){
    int n = (i >> 7) & 511;
    float sc = ((n >> 7) == 2) ? 2.88539008f : -1.44269504f;
    WIHS[i] = f2bf(wih[i] * sc);
    WHHS[i] = f2bf(whh[i] * sc);
  }
  for (int i = g0; i < NL*G_; i += stride){
    float sc = (((i & 511) >> 7) == 2) ? 2.88539008f : -1.44269504f;
    BSCL[i] = (bih[i] + bhh[i]) * sc;
  }
  if (g0 < 32) flags[g0] = 0;
}

// ---------------------------------------------------------------- fused pipelined scan
// 48 WGs: layer = wg/16, q = wg%16 (4 batches). Per step: 16 gx MFMAs
// (x@Wih, one step ahead) + 16 rec MFMAs (h@Whh, C = gx+bias) +
// duplicate-row select + gates. Layer l hands h to layer l+1 in 16-step
// chunks via release/acquire flags (R5/R9-proven, fresh addresses only).
// R11 change vs R9: x prefetch deepened to a 4-set register ring — step t
// loads x[t+4] into the set freed at step t-1, uses the set loaded 3 steps
// ago for gx[t+1]. Hides the ~900cy cross-XCD load latency of H1/H2 that
// R9 exposed every step.
#define STEPF(tcur, AXL, AXU, GCC, GCN) do { \
    bf16x8 af0 = *(const bf16x8*)((const char*)RBp + afo0); \
    bf16x8 af1 = *(const bf16x8*)((const char*)RBp + afo1); \
    bf16x8 af2 = *(const bf16x8*)((const char*)RBp + afo2); \
    bf16x8 af3 = *(const bf16x8*)((const char*)RBp + afo3); \
    f32x4 a0 = MF(af0, bwhh[0][0], GCC[0]); \
    f32x4 a1 = MF(af0, bwhh[1][0], GCC[1]); \
    f32x4 a2 = MF(af0, bwhh[2][0], GCC[2]); \
    f32x4 a3 = MF(af0, bwhh[3][0], GCC[3]); \
    a0 = MF(af1, bwhh[0][1], a0); a1 = MF(af1, bwhh[1][1], a1); \
    a2 = MF(af1, bwhh[2][1], a2); a3 = MF(af1, bwhh[3][1], a3); \
    a0 = MF(af2, bwhh[0][2], a0); a1 = MF(af2, bwhh[1][2], a1); \
    a2 = MF(af2, bwhh[2][2], a2); a3 = MF(af2, bwhh[3][2], a3); \
    a0 = MF(af3, bwhh[0][3], a0); a1 = MF(af3, bwhh[1][3], a1); \
    a2 = MF(af3, bwhh[2][3], a2); a3 = MF(af3, bwhh[3][3], a3); \
    { int tc_ = (tcur) + 4; tc_ = tc_ > T_-1 ? T_-1 : tc_; \
      const uint16_t* xb_ = Xin + (size_t)tc_ * H_; \
      AXL[0] = *(const bf16x8*)(xb_ + xo0); \
      AXL[1] = *(const bf16x8*)(xb_ + xo1); \
      AXL[2] = *(const bf16x8*)(xb_ + xo2); \
      AXL[3] = *(const bf16x8*)(xb_ + xo3); } \
    GCN[0] = MF(AXU[0], bwih[0][0], binit0); \
    GCN[1] = MF(AXU[0], bwih[1][0], binit1); \
    GCN[2] = MF(AXU[0], bwih[2][0], binit2); \
    GCN[3] = MF(AXU[0], bwih[3][0], binit3); \
    GCN[0] = MF(AXU[1], bwih[0][1], GCN[0]); GCN[1] = MF(AXU[1], bwih[1][1], GCN[1]); \
    GCN[2] = MF(AXU[1], bwih[2][1], GCN[2]); GCN[3] = MF(AXU[1], bwih[3][1], GCN[3]); \
    GCN[0] = MF(AXU[2], bwih[0][2], GCN[0]); GCN[1] = MF(AXU[2], bwih[1][2], GCN[1]); \
    GCN[2] = MF(AXU[2], bwih[2][2], GCN[2]); GCN[3] = MF(AXU[2], bwih[3][2], GCN[3]); \
    GCN[0] = MF(AXU[3], bwih[0][3], GCN[0]); GCN[1] = MF(AXU[3], bwih[1][3], GCN[1]); \
    GCN[2] = MF(AXU[3], bwih[2][3], GCN[2]); GCN[3] = MF(AXU[3], bwih[3][3], GCN[3]); \
    float p0 = hiB1 ? a0[1] : a0[0]; float q0 = hiB1 ? a0[3] : a0[2]; \
    float p1 = hiB1 ? a1[1] : a1[0]; float q1 = hiB1 ? a1[3] : a1[2]; \
    float p2 = hiB1 ? a2[1] : a2[0]; float q2 = hiB1 ? a2[3] : a2[2]; \
    float p3 = hiB1 ? a3[1] : a3[0]; float q3 = hiB1 ? a3[3] : a3[2]; \
    float x0 = hiB2 ? q0 : p0; \
    float x1 = hiB2 ? q1 : p1; \
    float x2 = hiB2 ? q2 : p2; \
    float x3 = hiB2 ? q3 : p3; \
    float iv = __builtin_amdgcn_rcpf(1.0f + __builtin_amdgcn_exp2f(x0)); \
    float fv = __builtin_amdgcn_rcpf(1.0f + __builtin_amdgcn_exp2f(x1)); \
    float gt = __builtin_amdgcn_rcpf(1.0f + __builtin_amdgcn_exp2f(x2)); \
    float ov = __builtin_amdgcn_rcpf(1.0f + __builtin_amdgcn_exp2f(x3)); \
    float gv = __builtin_fmaf(-2.0f, gt, 1.0f); \
    cst = fv * cst + iv * gv; \
    float tt = __builtin_amdgcn_rcpf(1.0f + __builtin_amdgcn_exp2f(2.88539008f * cst)); \
    float th = __builtin_fmaf(-2.0f, tt, 1.0f); \
    float hval = ov * th; \
    uint32_t hp; \
    asm("v_cvt_pk_bf16_f32 %0, %1, %2" : "=v"(hp) : "v"(hval), "v"(hval)); \
    *(uint16_t*)((char*)WBp + hw_off) = (uint16_t)hp; \
    if (layer < 2){ \
      Hout[houtBase + (size_t)(tcur)*H_] = (uint16_t)hp; \
    } else if ((tcur) == T_-1){ \
      hlast[(b0+hi)*H_ + j] = hval; \
    } \
    wg_barrier(); \
    { uint16_t* tmp_ = RBp; RBp = WBp; WBp = tmp_; } \
  } while(0)

__global__ __launch_bounds__(512, 2) void fused_kernel(
    const uint16_t* __restrict__ A0, uint16_t* __restrict__ H1,
    uint16_t* __restrict__ H2, const uint16_t* __restrict__ WIHS,
    const uint16_t* __restrict__ WHHS, const float* __restrict__ BSCL,
    float* __restrict__ hlast, int* __restrict__ flags){
  __shared__ uint16_t hb0[4*128];
  __shared__ uint16_t hb1[4*128];
  int tid = threadIdx.x;
  int wg = blockIdx.x;
  int layer = wg >> 4, q = wg & 15;
  int b0 = q * 4;
  int w = tid >> 6, l = tid & 63, lo = l & 15, hi = l >> 4;
  int j = w*16 + lo;
  bool hiB1 = (hi & 1), hiB2 = (hi & 2);

  const uint16_t* Xin = (layer == 0) ? A0 : ((layer == 1) ? H1 : H2);
  uint16_t* Hout = (layer == 0) ? H1 : H2;   // unused for layer 2
  int* flgP = flags + layer*16 + q;          // producer flag (layer<2)
  int* flgC = flags + (layer-1)*16 + q;      // consumer flag (layer>0)

  const uint16_t* wihL = WIHS + layer*G_*H_;
  const uint16_t* whhL = WHHS + layer*G_*H_;

  bf16x8 bwih[4][4], bwhh[4][4];
#pragma unroll
  for (int g = 0; g < 4; ++g)
#pragma unroll
    for (int kc = 0; kc < 4; ++kc){
      bwih[g][kc] = *(const bf16x8*)(wihL + (g*128 + j)*H_ + kc*32 + hi*8);
      bwhh[g][kc] = *(const bf16x8*)(whhL + (g*128 + j)*H_ + kc*32 + hi*8);
    }
#pragma unroll
  for (int g = 0; g < 4; ++g)
#pragma unroll
    for (int kc = 0; kc < 4; ++kc)
      asm volatile("" : "+v"(bwhh[g][kc]));

  float bs0 = BSCL[layer*G_ +       j];
  float bs1 = BSCL[layer*G_ + 128 + j];
  float bs2 = BSCL[layer*G_ + 256 + j];
  float bs3 = BSCL[layer*G_ + 384 + j];
  f32x4 binit0 = {bs0,bs0,bs0,bs0};
  f32x4 binit1 = {bs1,bs1,bs1,bs1};
  f32x4 binit2 = {bs2,bs2,bs2,bs2};
  f32x4 binit3 = {bs3,bs3,bs3,bs3};

  // A-frag h-tile offsets (R4-verified swizzle, 0 bank conflicts)
  int rb = lo & 3;
  int swr = ((rb & 1) << 6) | ((rb >> 1) << 5);
  int afo0 = rb*256 + ((  0 + hi*16) ^ swr);
  int afo1 = rb*256 + (( 64 + hi*16) ^ swr);
  int afo2 = rb*256 + ((128 + hi*16) ^ swr);
  int afo3 = rb*256 + ((192 + hi*16) ^ swr);
  int hw_off = hi*256 + ((j*2) ^ (((hi & 1) << 6) | ((hi >> 1) << 5)));
  size_t houtBase = (size_t)(b0 + hi) * T_ * H_ + j;

  // x A-frag global offsets (row rb duplicated across lo groups)
  int xo0 = (b0 + rb)*T_*H_ +  0*32 + hi*8;
  int xo1 = (b0 + rb)*T_*H_ +  1*32 + hi*8;
  int xo2 = (b0 + rb)*T_*H_ +  2*32 + hi*8;
  int xo3 = (b0 + rb)*T_*H_ +  3*32 + hi*8;

  float cst = 0.0f;
  hb0[tid] = 0;
  hb1[tid] = 0;

  if (layer > 0 && tid == 0){
    while (__hip_atomic_load(flgC, __ATOMIC_ACQUIRE, __HIP_MEMORY_SCOPE_AGENT) < 2)
      __builtin_amdgcn_s_sleep(8);
  }
  __syncthreads();

  // 4-set x register ring: set p holds x[t] with t % 4 == p.
  bf16x8 ax0[4], ax1[4], ax2[4], ax3[4];
#define LOADSET(AX, tt) do { \
    const uint16_t* xb = Xin + (size_t)(tt) * H_; \
    AX[0] = *(const bf16x8*)(xb + xo0); \
    AX[1] = *(const bf16x8*)(xb + xo1); \
    AX[2] = *(const bf16x8*)(xb + xo2); \
    AX[3] = *(const bf16x8*)(xb + xo3); \
  } while(0)
  LOADSET(ax0, 0);
  LOADSET(ax1, 1);
  LOADSET(ax2, 2);
  LOADSET(ax3, 3);

  f32x4 gE[4], gO[4];
  gE[0] = MF(ax0[0], bwih[0][0], binit0);
  gE[1] = MF(ax0[0], bwih[1][0], binit1);
  gE[2] = MF(ax0[0], bwih[2][0], binit2);
  gE[3] = MF(ax0[0], bwih[3][0], binit3);
#pragma unroll
  for (int kc = 1; kc < 4; ++kc){
    gE[0] = MF(ax0[kc], bwih[0][kc], gE[0]);
    gE[1] = MF(ax0[kc], bwih[1][kc], gE[1]);
    gE[2] = MF(ax0[kc], bwih[2][kc], gE[2]);
    gE[3] = MF(ax0[kc], bwih[3][kc], gE[3]);
  }

  uint16_t* RBp = hb0;
  uint16_t* WBp = hb1;

  for (int c = 0; c < NCH; ++c){
    int tb = c * CHK;
#pragma unroll
    for (int kk = 0; kk < 4; ++kk){
      int t = tb + kk*4;
      STEPF(t,   ax0, ax1, gE, gO);   // loads x[t+4] into ax0, gx[t+1] from ax1
      STEPF(t+1, ax1, ax2, gO, gE);
      STEPF(t+2, ax2, ax3, gE, gO);
      STEPF(t+3, ax3, ax0, gO, gE);
    }
    if (layer < 2){
      asm volatile("s_waitcnt vmcnt(0)" ::: "memory");
      __syncthreads();
      if (tid == 0)
        __hip_atomic_store(flgP, c + 1, __ATOMIC_RELEASE, __HIP_MEMORY_SCOPE_AGENT);
    }
    if (layer > 0 && c + 1 < NCH){
      int target = c + 3; if (target > NCH) target = NCH;
      if (tid == 0){
        while (__hip_atomic_load(flgC, __ATOMIC_ACQUIRE, __HIP_MEMORY_SCOPE_AGENT) < target)
          __builtin_amdgcn_s_sleep(8);
      }
      __syncthreads();
    }
  }
}

// ---------------------------------------------------------------- final MLP (fp32)
__global__ void mlp_kernel(const float* __restrict__ hlast,
    const float* __restrict__ w1, const float* __restrict__ b1,
    const float* __restrict__ w2, const float* __restrict__ b2,
    const float* __restrict__ w3, const float* __restrict__ b3,
    float* __restrict__ out){
  int b = blockIdx.x, t = threadIdx.x;
  __shared__ float sh[128];
  __shared__ float s1[64];
  __shared__ float s2[32];
  sh[t] = hlast[b*H_ + t];
  sh[t+64] = hlast[b*H_ + t + 64];
  __syncthreads();
  if (t < 64){
    float d = b1[t];
    for (int k = 0; k < 128; ++k) d += sh[k]*w1[t*128+k];
    s1[t] = d;
  }
  __syncthreads();
  if (t < 32){
    float d = b2[t];
    for (int k = 0; k < 64; ++k) d += s1[k]*w2[t*64+k];
    s2[t] = d;
  }
  __syncthreads();
  if (t < 10){
    float d = b3[t];
    for (int k = 0; k < 32; ++k) d += s2[k]*w3[t*32+k];
    out[b*OUT_ + t] = d;
  }
}

// ---------------------------------------------------------------- launch
extern "C" void kernel_launch(void* const* d_in, const int* in_sizes, int n_in,
                              void* d_out, int out_size, void* d_ws, size_t ws_size,
                              hipStream_t stream){
  const float* x   = (const float*)d_in[0];
  const float* wih = (const float*)d_in[1];
  const float* whh = (const float*)d_in[2];
  const float* bih = (const float*)d_in[3];
  const float* bhh = (const float*)d_in[4];
  const float* w1  = (const float*)d_in[5];
  const float* b1  = (const float*)d_in[6];
  const float* w2  = (const float*)d_in[7];
  const float* b2  = (const float*)d_in[8];
  const float* w3  = (const float*)d_in[9];
  const float* b3  = (const float*)d_in[10];
  float* out = (float*)d_out;

  char* ws = (char*)d_ws;
  uint16_t* A0   = (uint16_t*)(ws);                     // 33554432 B
  uint16_t* H1   = (uint16_t*)(ws + 33554432);          // 33554432 B
  uint16_t* H2   = (uint16_t*)(ws + 67108864);          // 33554432 B
  uint16_t* WIHS = (uint16_t*)(ws + 100663296);         // 393216 B
  uint16_t* WHHS = (uint16_t*)(ws + 101056512);         // 393216 B
  float*    BSCL = (float*)   (ws + 101449728);         // 6144 B
  float*    HL   = (float*)   (ws + 101455872);         // 32768 B
  int*      FLG  = (int*)     (ws + 101488640);         // 128 B

  prep_kernel<<<2048, 256, 0, stream>>>(x, wih, whh, bih, bhh, A0, WIHS, WHHS, BSCL, FLG);
  fused_kernel<<<48, 512, 0, stream>>>(A0, H1, H2, WIHS, WHHS, BSCL, HL, FLG);
  mlp_kernel<<<B_, 64, 0, stream>>>(HL, w1, b1, w2, b2, w3, b3, out);
}

// Round 12
// 2097.671 us; speedup vs baseline: 1.8413x; 1.8413x over previous
//
#include <hip/hip_runtime.h>
#include <stdint.h>

#define B_ 64
#define T_ 2048
#define H_ 128
#define G_ 512
#define NL 3
#define OUT_ 10
#define CHK 16
#define NCH (T_/CHK)

typedef __attribute__((ext_vector_type(8))) short bf16x8;
typedef __attribute__((ext_vector_type(4))) float f32x4;

#define MF(A,BW,C) __builtin_amdgcn_mfma_f32_16x16x32_bf16(A,BW,C,0,0,0)

__device__ __forceinline__ uint16_t f2bf(float f){
  union { float f; uint32_t u; } v; v.f = f;
  uint32_t u = v.u;
  uint32_t r = (u + 0x7FFFu + ((u >> 16) & 1u)) >> 16;
  return (uint16_t)r;
}

// Barrier WITHOUT vmcnt(0) drain: LDS ordering only.
__device__ __forceinline__ void wg_barrier(){
  asm volatile("s_waitcnt lgkmcnt(0)" ::: "memory");
  __builtin_amdgcn_sched_barrier(0);
  __builtin_amdgcn_s_barrier();
  __builtin_amdgcn_sched_barrier(0);
}

// ---------------------------------------------------------------- prep
// Weights pre-scaled per gate (i,f,o: -log2e; g: +2*log2e) so gates become
// rcp(1+exp2(x)); bias likewise pre-scaled (folded into MFMA C-init).
__global__ void prep_kernel(const float* __restrict__ x,
                            const float* __restrict__ wih, const float* __restrict__ whh,
                            const float* __restrict__ bih, const float* __restrict__ bhh,
                            uint16_t* __restrict__ A0, uint16_t* __restrict__ WIHS,
                            uint16_t* __restrict__ WHHS, float* __restrict__ BSCL,
                            int* __restrict__ flags){
  int stride = gridDim.x * blockDim.x;
  int g0 = blockIdx.x * blockDim.x + threadIdx.x;
  for (int i = g0; i < B_*T_*H_; i += stride) A0[i] = f2bf(x[i]);
  for (int i = g0; i < NL*G_*H_; i += stride){
    int n = (i >> 7) & 511;
    float sc = ((n >> 7) == 2) ? 2.88539008f : -1.44269504f;
    WIHS[i] = f2bf(wih[i] * sc);
    WHHS[i] = f2bf(whh[i] * sc);
  }
  for (int i = g0; i < NL*G_; i += stride){
    float sc = (((i & 511) >> 7) == 2) ? 2.88539008f : -1.44269504f;
    BSCL[i] = (bih[i] + bhh[i]) * sc;
  }
  if (g0 < 32) flags[g0] = 0;
}

// ---------------------------------------------------------------- fused pipelined scan
// 48 WGs: layer = wg/16, q = wg%16 (4 batches). R12: K=256 fused chain —
// per gate-block, ONE 8-deep MFMA chain: C=bias, 4 MFMAs on x-frags (Wih),
// 4 MFMAs on h-frags (Whh). x-part is h-independent and issues under the
// h ds_read shadow. No separate gx accumulator state. Numerics identical
// to R9 (same accumulation order). Layer handoff: R5/R9-proven chunk flags.
// x double-buffer: step t consumes set (t&1), then reloads it with x[t+2].
#define STEPF(tcur, AX) do { \
    bf16x8 af0 = *(const bf16x8*)((const char*)RBp + afo0); \
    bf16x8 af1 = *(const bf16x8*)((const char*)RBp + afo1); \
    bf16x8 af2 = *(const bf16x8*)((const char*)RBp + afo2); \
    bf16x8 af3 = *(const bf16x8*)((const char*)RBp + afo3); \
    f32x4 a0 = MF(AX[0], bwih[0][0], binit0); \
    f32x4 a1 = MF(AX[0], bwih[1][0], binit1); \
    f32x4 a2 = MF(AX[0], bwih[2][0], binit2); \
    f32x4 a3 = MF(AX[0], bwih[3][0], binit3); \
    a0 = MF(AX[1], bwih[0][1], a0); a1 = MF(AX[1], bwih[1][1], a1); \
    a2 = MF(AX[1], bwih[2][1], a2); a3 = MF(AX[1], bwih[3][1], a3); \
    a0 = MF(AX[2], bwih[0][2], a0); a1 = MF(AX[2], bwih[1][2], a1); \
    a2 = MF(AX[2], bwih[2][2], a2); a3 = MF(AX[2], bwih[3][2], a3); \
    a0 = MF(AX[3], bwih[0][3], a0); a1 = MF(AX[3], bwih[1][3], a1); \
    a2 = MF(AX[3], bwih[2][3], a2); a3 = MF(AX[3], bwih[3][3], a3); \
    { int tc_ = (tcur) + 2; tc_ = tc_ > T_-1 ? T_-1 : tc_; \
      const uint16_t* xb_ = Xin + (size_t)tc_ * H_; \
      AX[0] = *(const bf16x8*)(xb_ + xo0); \
      AX[1] = *(const bf16x8*)(xb_ + xo1); \
      AX[2] = *(const bf16x8*)(xb_ + xo2); \
      AX[3] = *(const bf16x8*)(xb_ + xo3); } \
    a0 = MF(af0, bwhh[0][0], a0); a1 = MF(af0, bwhh[1][0], a1); \
    a2 = MF(af0, bwhh[2][0], a2); a3 = MF(af0, bwhh[3][0], a3); \
    a0 = MF(af1, bwhh[0][1], a0); a1 = MF(af1, bwhh[1][1], a1); \
    a2 = MF(af1, bwhh[2][1], a2); a3 = MF(af1, bwhh[3][1], a3); \
    a0 = MF(af2, bwhh[0][2], a0); a1 = MF(af2, bwhh[1][2], a1); \
    a2 = MF(af2, bwhh[2][2], a2); a3 = MF(af2, bwhh[3][2], a3); \
    a0 = MF(af3, bwhh[0][3], a0); a1 = MF(af3, bwhh[1][3], a1); \
    a2 = MF(af3, bwhh[2][3], a2); a3 = MF(af3, bwhh[3][3], a3); \
    float p0 = hiB1 ? a0[1] : a0[0]; float q0 = hiB1 ? a0[3] : a0[2]; \
    float p1 = hiB1 ? a1[1] : a1[0]; float q1 = hiB1 ? a1[3] : a1[2]; \
    float p2 = hiB1 ? a2[1] : a2[0]; float q2 = hiB1 ? a2[3] : a2[2]; \
    float p3 = hiB1 ? a3[1] : a3[0]; float q3 = hiB1 ? a3[3] : a3[2]; \
    float x0 = hiB2 ? q0 : p0; \
    float x1 = hiB2 ? q1 : p1; \
    float x2 = hiB2 ? q2 : p2; \
    float x3 = hiB2 ? q3 : p3; \
    float iv = __builtin_amdgcn_rcpf(1.0f + __builtin_amdgcn_exp2f(x0)); \
    float fv = __builtin_amdgcn_rcpf(1.0f + __builtin_amdgcn_exp2f(x1)); \
    float gt = __builtin_amdgcn_rcpf(1.0f + __builtin_amdgcn_exp2f(x2)); \
    float ov = __builtin_amdgcn_rcpf(1.0f + __builtin_amdgcn_exp2f(x3)); \
    float gv = __builtin_fmaf(-2.0f, gt, 1.0f); \
    cst = fv * cst + iv * gv; \
    float tt = __builtin_amdgcn_rcpf(1.0f + __builtin_amdgcn_exp2f(2.88539008f * cst)); \
    float th = __builtin_fmaf(-2.0f, tt, 1.0f); \
    float hval = ov * th; \
    uint32_t hp; \
    asm("v_cvt_pk_bf16_f32 %0, %1, %2" : "=v"(hp) : "v"(hval), "v"(hval)); \
    *(uint16_t*)((char*)WBp + hw_off) = (uint16_t)hp; \
    if (layer < 2){ \
      Hout[houtBase + (size_t)(tcur)*H_] = (uint16_t)hp; \
    } else if ((tcur) == T_-1){ \
      hlast[(b0+hi)*H_ + j] = hval; \
    } \
    wg_barrier(); \
    { uint16_t* tmp_ = RBp; RBp = WBp; WBp = tmp_; } \
  } while(0)

__global__ __launch_bounds__(512, 2) void fused_kernel(
    const uint16_t* __restrict__ A0, uint16_t* __restrict__ H1,
    uint16_t* __restrict__ H2, const uint16_t* __restrict__ WIHS,
    const uint16_t* __restrict__ WHHS, const float* __restrict__ BSCL,
    float* __restrict__ hlast, int* __restrict__ flags){
  __shared__ uint16_t hb0[4*128];
  __shared__ uint16_t hb1[4*128];
  int tid = threadIdx.x;
  int wg = blockIdx.x;
  int layer = wg >> 4, q = wg & 15;
  int b0 = q * 4;
  int w = tid >> 6, l = tid & 63, lo = l & 15, hi = l >> 4;
  int j = w*16 + lo;
  bool hiB1 = (hi & 1), hiB2 = (hi & 2);

  const uint16_t* Xin = (layer == 0) ? A0 : ((layer == 1) ? H1 : H2);
  uint16_t* Hout = (layer == 0) ? H1 : H2;   // unused for layer 2
  int* flgP = flags + layer*16 + q;          // producer flag (layer<2)
  int* flgC = flags + (layer-1)*16 + q;      // consumer flag (layer>0)

  const uint16_t* wihL = WIHS + layer*G_*H_;
  const uint16_t* whhL = WHHS + layer*G_*H_;

  bf16x8 bwih[4][4], bwhh[4][4];
#pragma unroll
  for (int g = 0; g < 4; ++g)
#pragma unroll
    for (int kc = 0; kc < 4; ++kc){
      bwih[g][kc] = *(const bf16x8*)(wihL + (g*128 + j)*H_ + kc*32 + hi*8);
      bwhh[g][kc] = *(const bf16x8*)(whhL + (g*128 + j)*H_ + kc*32 + hi*8);
    }

  float bs0 = BSCL[layer*G_ +       j];
  float bs1 = BSCL[layer*G_ + 128 + j];
  float bs2 = BSCL[layer*G_ + 256 + j];
  float bs3 = BSCL[layer*G_ + 384 + j];
  f32x4 binit0 = {bs0,bs0,bs0,bs0};
  f32x4 binit1 = {bs1,bs1,bs1,bs1};
  f32x4 binit2 = {bs2,bs2,bs2,bs2};
  f32x4 binit3 = {bs3,bs3,bs3,bs3};

  // A-frag h-tile offsets (R4-verified swizzle, 0 bank conflicts)
  int rb = lo & 3;
  int swr = ((rb & 1) << 6) | ((rb >> 1) << 5);
  int afo0 = rb*256 + ((  0 + hi*16) ^ swr);
  int afo1 = rb*256 + (( 64 + hi*16) ^ swr);
  int afo2 = rb*256 + ((128 + hi*16) ^ swr);
  int afo3 = rb*256 + ((192 + hi*16) ^ swr);
  int hw_off = hi*256 + ((j*2) ^ (((hi & 1) << 6) | ((hi >> 1) << 5)));
  size_t houtBase = (size_t)(b0 + hi) * T_ * H_ + j;

  // x A-frag global offsets (row rb duplicated across lo groups)
  int xo0 = (b0 + rb)*T_*H_ +  0*32 + hi*8;
  int xo1 = (b0 + rb)*T_*H_ +  1*32 + hi*8;
  int xo2 = (b0 + rb)*T_*H_ +  2*32 + hi*8;
  int xo3 = (b0 + rb)*T_*H_ +  3*32 + hi*8;

  float cst = 0.0f;
  hb0[tid] = 0;
  hb1[tid] = 0;

  if (layer > 0 && tid == 0){
    while (__hip_atomic_load(flgC, __ATOMIC_ACQUIRE, __HIP_MEMORY_SCOPE_AGENT) < 2)
      __builtin_amdgcn_s_sleep(8);
  }
  __syncthreads();

  bf16x8 axA[4], axB[4];
  {
    const uint16_t* xb = Xin;          // t = 0
    axA[0] = *(const bf16x8*)(xb + xo0);
    axA[1] = *(const bf16x8*)(xb + xo1);
    axA[2] = *(const bf16x8*)(xb + xo2);
    axA[3] = *(const bf16x8*)(xb + xo3);
    xb = Xin + H_;                     // t = 1
    axB[0] = *(const bf16x8*)(xb + xo0);
    axB[1] = *(const bf16x8*)(xb + xo1);
    axB[2] = *(const bf16x8*)(xb + xo2);
    axB[3] = *(const bf16x8*)(xb + xo3);
  }

  uint16_t* RBp = hb0;
  uint16_t* WBp = hb1;

  for (int c = 0; c < NCH; ++c){
    int tb = c * CHK;
#pragma unroll
    for (int kk = 0; kk < 4; ++kk){
      int t = tb + kk*4;
      STEPF(t,   axA);   // consumes x[t],   reloads axA with x[t+2]
      STEPF(t+1, axB);   // consumes x[t+1], reloads axB with x[t+3]
      STEPF(t+2, axA);
      STEPF(t+3, axB);
    }
    if (layer < 2){
      asm volatile("s_waitcnt vmcnt(0)" ::: "memory");
      __syncthreads();
      if (tid == 0)
        __hip_atomic_store(flgP, c + 1, __ATOMIC_RELEASE, __HIP_MEMORY_SCOPE_AGENT);
    }
    if (layer > 0 && c + 1 < NCH){
      int target = c + 3; if (target > NCH) target = NCH;
      if (tid == 0){
        while (__hip_atomic_load(flgC, __ATOMIC_ACQUIRE, __HIP_MEMORY_SCOPE_AGENT) < target)
          __builtin_amdgcn_s_sleep(8);
      }
      __syncthreads();
    }
  }
}

// ---------------------------------------------------------------- final MLP (fp32)
__global__ void mlp_kernel(const float* __restrict__ hlast,
    const float* __restrict__ w1, const float* __restrict__ b1,
    const float* __restrict__ w2, const float* __restrict__ b2,
    const float* __restrict__ w3, const float* __restrict__ b3,
    float* __restrict__ out){
  int b = blockIdx.x, t = threadIdx.x;
  __shared__ float sh[128];
  __shared__ float s1[64];
  __shared__ float s2[32];
  sh[t] = hlast[b*H_ + t];
  sh[t+64] = hlast[b*H_ + t + 64];
  __syncthreads();
  if (t < 64){
    float d = b1[t];
    for (int k = 0; k < 128; ++k) d += sh[k]*w1[t*128+k];
    s1[t] = d;
  }
  __syncthreads();
  if (t < 32){
    float d = b2[t];
    for (int k = 0; k < 64; ++k) d += s1[k]*w2[t*64+k];
    s2[t] = d;
  }
  __syncthreads();
  if (t < 10){
    float d = b3[t];
    for (int k = 0; k < 32; ++k) d += s2[k]*w3[t*32+k];
    out[b*OUT_ + t] = d;
  }
}

// ---------------------------------------------------------------- launch
extern "C" void kernel_launch(void* const* d_in, const int* in_sizes, int n_in,
                              void* d_out, int out_size, void* d_ws, size_t ws_size,
                              hipStream_t stream){
  const float* x   = (const float*)d_in[0];
  const float* wih = (const float*)d_in[1];
  const float* whh = (const float*)d_in[2];
  const float* bih = (const float*)d_in[3];
  const float* bhh = (const float*)d_in[4];
  const float* w1  = (const float*)d_in[5];
  const float* b1  = (const float*)d_in[6];
  const float* w2  = (const float*)d_in[7];
  const float* b2  = (const float*)d_in[8];
  const float* w3  = (const float*)d_in[9];
  const float* b3  = (const float*)d_in[10];
  float* out = (float*)d_out;

  char* ws = (char*)d_ws;
  uint16_t* A0   = (uint16_t*)(ws);                     // 33554432 B
  uint16_t* H1   = (uint16_t*)(ws + 33554432);          // 33554432 B
  uint16_t* H2   = (uint16_t*)(ws + 67108864);          // 33554432 B
  uint16_t* WIHS = (uint16_t*)(ws + 100663296);         // 393216 B
  uint16_t* WHHS = (uint16_t*)(ws + 101056512);         // 393216 B
  float*    BSCL = (float*)   (ws + 101449728);         // 6144 B
  float*    HL   = (float*)   (ws + 101455872);         // 32768 B
  int*      FLG  = (int*)     (ws + 101488640);         // 128 B

  prep_kernel<<<2048, 256, 0, stream>>>(x, wih, whh, bih, bhh, A0, WIHS, WHHS, BSCL, FLG);
  fused_kernel<<<48, 512, 0, stream>>>(A0, H1, H2, WIHS, WHHS, BSCL, HL, FLG);
  mlp_kernel<<<B_, 64, 0, stream>>>(HL, w1, b1, w2, b2, w3, b3, out);
}